// Round 13
// baseline (153.239 us; speedup 1.0000x reference)
//
#include <hip/hip_runtime.h>

// LR_PINN_phase2_midout: fused 4-stage tiny MLP, N=262144, H=256, R=32.
// R13 = R12 + (A) inv-feeding + (B) manual unroll-2 of the k<2 t-loops.
// R12 post-mortem: occupancy doubled (56%) but wall flat -> issue-bound
// (busy ~143k cyc/SIMD at both 4 and 8 waves). Cut issue cycles:
//  (A) emit inv = rcp(exp2(y)+1) (3 instr, no clamp: rcp(inf)=0 exact)
//      instead of tanh = fma(-2,inv,1): fold -2 into ctf & ew, init GEMM1
//      accs with rowsums sum_j(alpha*Ct[r][j]) and epilogue with ewsum.
//      Numerics HW-verified in R8 (absmax 7.3e-4 < 1.52e-3 threshold).
//  (B) k<2 loops: 8 bodies x 2 t-tiles -> half the pointer/branch glue,
//      2x in-body ILP. Live set ~60 of the 64-reg/wave budget at 8 waves.
//
// Kept from R12: rwf in global scratch (L2-resident; LDS 52 KB -> 2 blocks/
// CU -> 8 waves/SIMD), mfma_f32_16x16x16f16 layout-closed chain (C/D
// row=4q+reg == next B-frag k=4q+jj), fragment-ordered conflict-free
// LDS/global reads (base+lane*8), dual point streams, v_cvt_pkrtz packing,
// tanh scale 2*log2e folded into w0/w1/bb and rwf at staging.

typedef _Float16 half4_t __attribute__((ext_vector_type(4)));
typedef __fp16   fp16x2  __attribute__((ext_vector_type(2)));
typedef float    float4_t __attribute__((ext_vector_type(4)));

#define TANH_SCALE 2.885390081777927f  // 2*log2(e); exp2(S*x) == exp(2x)
#define MFMA16 __builtin_amdgcn_mfma_f32_16x16x16f16
#define NFRAG (3 * 16 * 2 * 64)        // 6144 half4 entries per matrix

namespace {

struct alignas(16) Smem {
  // entry index e = ((k*16+t)*2+sel)*64+lane ; one half4 (8 B) per lane.
  half4_t ctf[NFRAG];               // 48 KB: -2 * alpha * Ct[sel*16+m][16t+4q+jj]
  float w0[256], w1[256], bb[256];  // pre-scaled by S
  float ew[256];                    // -2 * end_w
  float rsC[3 * 32];                // rowsums: sum_j alpha*Ct[r][j]
};

__device__ __forceinline__ half4_t pack4(float4_t v) {
  union { fp16x2 f2[2]; half4_t h4; } u;
  u.f2[0] = __builtin_amdgcn_cvt_pkrtz(v.x, v.y);
  u.f2[1] = __builtin_amdgcn_cvt_pkrtz(v.z, v.w);
  return u.h4;
}

// inv = 1/(1+exp2(y)); tanh(x) = 1 - 2*inv (the -2/+1 live in weights/sums).
// No clamp needed: e=inf -> rcp(inf)=0 exact; e->0 -> inv->1 exact.
__device__ __forceinline__ float inv_pre(float y) {
  return __builtin_amdgcn_rcpf(__builtin_amdgcn_exp2f(y) + 1.0f);
}

__device__ __forceinline__ half4_t inv4(float4_t v) {
  float4_t r;
  r.x = inv_pre(v.x); r.y = inv_pre(v.y);
  r.z = inv_pre(v.z); r.w = inv_pre(v.w);
  return pack4(r);
}

// ---- pre-kernel: stage rwf fragments (S-prescaled fp16) into d_ws ----
__global__ __launch_bounds__(1024) void stage_rwf(
    const float* __restrict__ r0, const float* __restrict__ r1,
    const float* __restrict__ r2, half4_t* __restrict__ ws)
{
  const int e = blockIdx.x * 1024 + threadIdx.x;
  if (e >= NFRAG) return;
  const int lane_ = e & 63;
  const int sel   = (e >> 6) & 1;
  const int t_    = (e >> 7) & 15;
  const int k_    = e >> 11;
  const int m_ = lane_ & 15, q_ = lane_ >> 4;
  const float* rk = (k_ == 0) ? r0 : (k_ == 1) ? r1 : r2;
  const int j = 16 * t_ + m_;
  const int rr = sel * 16 + 4 * q_;
  half4_t v;
  v.x = (_Float16)(rk[j * 32 + rr + 0] * TANH_SCALE);
  v.y = (_Float16)(rk[j * 32 + rr + 1] * TANH_SCALE);
  v.z = (_Float16)(rk[j * 32 + rr + 2] * TANH_SCALE);
  v.w = (_Float16)(rk[j * 32 + rr + 3] * TANH_SCALE);
  ws[e] = v;
}

__global__ __launch_bounds__(1024)
__attribute__((amdgpu_waves_per_eu(8, 8)))
void pinn_fused(
    const float* __restrict__ xg, const float* __restrict__ tg,
    const float* __restrict__ sw, const float* __restrict__ sb,
    const float* __restrict__ ewp, const float* __restrict__ ebp,
    const float* __restrict__ c0, const float* __restrict__ c1,
    const float* __restrict__ c2, const float* __restrict__ a0,
    const float* __restrict__ a1, const float* __restrict__ a2,
    const half4_t* __restrict__ rwg, float* __restrict__ out, int n)
{
  __shared__ Smem sm;
  const int tid = threadIdx.x;

  // ---- stage ctf (with -2*alpha folded) into fragment-ordered LDS ----
  for (int e = tid; e < NFRAG; e += 1024) {
    const int lane_ = e & 63;
    const int sel   = (e >> 6) & 1;
    const int t_    = (e >> 7) & 15;
    const int k_    = e >> 11;
    const int m_ = lane_ & 15, q_ = lane_ >> 4;
    const float* ck = (k_ == 0) ? c0 : (k_ == 1) ? c1 : c2;
    const float* ak = (k_ == 0) ? a0 : (k_ == 1) ? a1 : a2;
    const int r = sel * 16 + m_;
    const float av = ak[r] * -2.0f;
    const int j0 = 16 * t_ + 4 * q_;
    half4_t v;
    v.x = (_Float16)(ck[(j0 + 0) * 32 + r] * av);
    v.y = (_Float16)(ck[(j0 + 1) * 32 + r] * av);
    v.z = (_Float16)(ck[(j0 + 2) * 32 + r] * av);
    v.w = (_Float16)(ck[(j0 + 3) * 32 + r] * av);
    sm.ctf[e] = v;
  }
  if (tid < 256) {
    sm.w0[tid] = sw[2 * tid] * TANH_SCALE;
    sm.w1[tid] = sw[2 * tid + 1] * TANH_SCALE;
    sm.bb[tid] = sb[tid] * TANH_SCALE;
    sm.ew[tid] = ewp[tid] * -2.0f;              // fold -2
  }
  __syncthreads();

  // ---- rowsums rsC[k][r] = sum_j alpha*Ct[r][j] = -0.5 * sum(ctf frags) ----
  if (tid < 96) {
    const int k_ = tid >> 5, r = tid & 31;
    const int sel = r >> 4, mm = r & 15;
    float s = 0.0f;
    for (int t = 0; t < 16; ++t)
      for (int qq = 0; qq < 4; ++qq) {
        const half4_t v = sm.ctf[((k_ * 16 + t) * 2 + sel) * 64 + 16 * qq + mm];
        s += (float)v.x + (float)v.y + (float)v.z + (float)v.w;
      }
    sm.rsC[k_ * 32 + r] = -0.5f * s;
  }
  __syncthreads();

  const int wave = tid >> 6;
  const int lane = tid & 63;
  const int m = lane & 15;   // point index (MFMA col / A-row / B-col)
  const int q = lane >> 4;   // quad
  const int wo = 4 * q;      // j = 16t + 4q + jj
  const float ebv = ebp[0];
  const int tiles = n >> 4;

  // per-lane ewsum: out = sum(ew) + sum((-2ew)*inv); sm.ew = -2*ew
  float ewsum = 0.0f;
  for (int t = 0; t < 16; ++t) {
    const float4_t e4 = *(const float4_t*)&sm.ew[t * 16 + wo];
    ewsum += e4.x + e4.y + e4.z + e4.w;
  }
  ewsum *= -0.5f;

  const float4_t z4 = {0.f, 0.f, 0.f, 0.f};  // hoisted MFMA C-operand zero

#pragma unroll 1
  for (int g = (blockIdx.x * 16 + wave) * 2; g < tiles; g += 16384) {
    const int n0 = g * 16;
    const int n1 = n0 + 16;
    const float xm0 = xg[n0 + m], tm0 = tg[n0 + m];
    const float xm1 = xg[n1 + m], tm1 = tg[n1 + m];

    // ---- phase0 fused with GEMM1(k=0); accs init with rowsums(0) ----
    const float4_t rs00 = *(const float4_t*)&sm.rsC[wo];
    const float4_t rs01 = *(const float4_t*)&sm.rsC[16 + wo];
    float4_t a00 = rs00, a01 = rs01, a10 = rs00, a11 = rs01;
    const half4_t* cp0 = &sm.ctf[lane];
#pragma unroll 1
    for (int t = 0; t < 16; ++t) {
      const int cb = t * 16 + wo;
      const float4_t w0v = *(const float4_t*)&sm.w0[cb];
      const float4_t w1v = *(const float4_t*)&sm.w1[cb];
      const float4_t bv  = *(const float4_t*)&sm.bb[cb];
      float4_t z0, z1;
      z0.x = fmaf(xm0, w0v.x, fmaf(tm0, w1v.x, bv.x));
      z1.x = fmaf(xm1, w0v.x, fmaf(tm1, w1v.x, bv.x));
      z0.y = fmaf(xm0, w0v.y, fmaf(tm0, w1v.y, bv.y));
      z1.y = fmaf(xm1, w0v.y, fmaf(tm1, w1v.y, bv.y));
      z0.z = fmaf(xm0, w0v.z, fmaf(tm0, w1v.z, bv.z));
      z1.z = fmaf(xm1, w0v.z, fmaf(tm1, w1v.z, bv.z));
      z0.w = fmaf(xm0, w0v.w, fmaf(tm0, w1v.w, bv.w));
      z1.w = fmaf(xm1, w0v.w, fmaf(tm1, w1v.w, bv.w));
      const half4_t h0 = inv4(z0);
      const half4_t h1 = inv4(z1);
      const half4_t cA = cp0[0], cB = cp0[64];
      a00 = MFMA16(cA, h0, a00, 0, 0, 0);
      a10 = MFMA16(cA, h1, a10, 0, 0, 0);
      a01 = MFMA16(cB, h0, a01, 0, 0, 0);
      a11 = MFMA16(cB, h1, a11, 0, 0, 0);
      cp0 += 128;
    }

#pragma unroll 1
    for (int k = 0; k < 2; ++k) {
      // acc holds true P (rowsum init); pack as next B-frag.
      const half4_t pA0 = pack4(a00), pB0 = pack4(a01);
      const half4_t pA1 = pack4(a10), pB1 = pack4(a11);
      const float4_t rsA = *(const float4_t*)&sm.rsC[(k + 1) * 32 + wo];
      const float4_t rsB = *(const float4_t*)&sm.rsC[(k + 1) * 32 + 16 + wo];
      float4_t n00 = rsA, n01 = rsB, n10 = rsA, n11 = rsB;
      const half4_t* rp = &rwg[k * 2048 + lane];   // global, L2-resident
      const half4_t* cp = &sm.ctf[(k + 1) * 2048 + lane];
#pragma unroll 1
      for (int t = 0; t < 8; ++t) {  // unroll-2: two t-tiles per body
        const half4_t rA = rp[0], rB = rp[64];
        const half4_t rC = rp[128], rD = rp[192];
        const half4_t cA = cp[0], cB = cp[64];
        const half4_t cC = cp[128], cD = cp[192];
        float4_t u0 = MFMA16(rA, pA0, z4, 0, 0, 0);
        float4_t u1 = MFMA16(rA, pA1, z4, 0, 0, 0);
        float4_t v0 = MFMA16(rC, pA0, z4, 0, 0, 0);
        float4_t v1 = MFMA16(rC, pA1, z4, 0, 0, 0);
        u0 = MFMA16(rB, pB0, u0, 0, 0, 0);
        u1 = MFMA16(rB, pB1, u1, 0, 0, 0);
        v0 = MFMA16(rD, pB0, v0, 0, 0, 0);
        v1 = MFMA16(rD, pB1, v1, 0, 0, 0);
        const half4_t h0 = inv4(u0);
        const half4_t h1 = inv4(u1);
        const half4_t h2 = inv4(v0);
        const half4_t h3 = inv4(v1);
        n00 = MFMA16(cA, h0, n00, 0, 0, 0);
        n10 = MFMA16(cA, h1, n10, 0, 0, 0);
        n01 = MFMA16(cB, h0, n01, 0, 0, 0);
        n11 = MFMA16(cB, h1, n11, 0, 0, 0);
        n00 = MFMA16(cC, h2, n00, 0, 0, 0);
        n10 = MFMA16(cC, h3, n10, 0, 0, 0);
        n01 = MFMA16(cD, h2, n01, 0, 0, 0);
        n11 = MFMA16(cD, h3, n11, 0, 0, 0);
        rp += 256; cp += 256;
      }
      a00 = n00; a01 = n01; a10 = n10; a11 = n11;
    }

    // ---- k=2: GEMM2(2) fused with the end_w dot; ssum init = ewsum ----
    float ssum0 = ewsum, ssum1 = ewsum;
    {
      const half4_t pA0 = pack4(a00), pB0 = pack4(a01);
      const half4_t pA1 = pack4(a10), pB1 = pack4(a11);
      const half4_t* rp = &rwg[2 * 2048 + lane];
#pragma unroll 1
      for (int t = 0; t < 16; ++t) {
        const half4_t rA = rp[0], rB = rp[64];
        const float4_t ev = *(const float4_t*)&sm.ew[t * 16 + wo];  // -2*ew
        float4_t u0 = MFMA16(rA, pA0, z4, 0, 0, 0);
        float4_t u1 = MFMA16(rA, pA1, z4, 0, 0, 0);
        u0 = MFMA16(rB, pB0, u0, 0, 0, 0);
        u1 = MFMA16(rB, pB1, u1, 0, 0, 0);
        ssum0 = fmaf(ev.x, inv_pre(u0.x), ssum0);
        ssum1 = fmaf(ev.x, inv_pre(u1.x), ssum1);
        ssum0 = fmaf(ev.y, inv_pre(u0.y), ssum0);
        ssum1 = fmaf(ev.y, inv_pre(u1.y), ssum1);
        ssum0 = fmaf(ev.z, inv_pre(u0.z), ssum0);
        ssum1 = fmaf(ev.z, inv_pre(u1.z), ssum1);
        ssum0 = fmaf(ev.w, inv_pre(u0.w), ssum0);
        ssum1 = fmaf(ev.w, inv_pre(u1.w), ssum1);
        rp += 128;
      }
    }

    // reduce each stream's partial dot over the 4 quads
    ssum0 += __shfl_xor(ssum0, 16);
    ssum0 += __shfl_xor(ssum0, 32);
    ssum1 += __shfl_xor(ssum1, 16);
    ssum1 += __shfl_xor(ssum1, 32);
    if (lane < 16) {
      out[n0 + m] = ssum0 + ebv;
      out[n1 + m] = ssum1 + ebv;
    }
  }
}

}  // namespace

extern "C" void kernel_launch(void* const* d_in, const int* in_sizes, int n_in,
                              void* d_out, int out_size, void* d_ws, size_t ws_size,
                              hipStream_t stream) {
  const float* xg  = (const float*)d_in[0];
  const float* tg  = (const float*)d_in[1];
  const float* sw  = (const float*)d_in[2];
  const float* sb  = (const float*)d_in[3];
  const float* ewp = (const float*)d_in[4];
  const float* ebp = (const float*)d_in[5];
  const float* c0  = (const float*)d_in[6];
  const float* c1  = (const float*)d_in[7];
  const float* c2  = (const float*)d_in[8];
  const float* r0  = (const float*)d_in[9];
  const float* r1  = (const float*)d_in[10];
  const float* r2  = (const float*)d_in[11];
  const float* a0  = (const float*)d_in[12];
  const float* a1  = (const float*)d_in[13];
  const float* a2  = (const float*)d_in[14];
  float* outp = (float*)d_out;
  half4_t* ws = (half4_t*)d_ws;   // 48 KB of rwf fragments

  const int n = in_sizes[0];  // 262144

  // stage rwf into d_ws (same stream: ordered before the main kernel)
  stage_rwf<<<(NFRAG + 1023) / 1024, 1024, 0, stream>>>(r0, r1, r2, ws);

  pinn_fused<<<512, 1024, 0, stream>>>(xg, tg, sw, sb, ewp, ebp,
                                       c0, c1, c2, a0, a1, a2,
                                       ws, outp, n);
}

// Round 14
// 143.266 us; speedup vs baseline: 1.0696x; 1.0696x over previous
//
#include <hip/hip_runtime.h>

// LR_PINN_phase2_midout: fused 4-stage tiny MLP, N=262144, H=256, R=32.
// R14 = R13 with the unroll-2 REVERTED (it spilled: WRITE 1->33.8 MB at the
// 64-reg/wave budget of 8 waves/SIMD) while KEEPING inv-feeding, which
// measurably cut VALU busy ~145k -> ~128k cyc/SIMD:
//   inv = rcp(exp2(y)+1) (no clamp: rcp(inf)=0 exact) replaces tanh;
//   -2 folded into ctf & ew; GEMM1 accs init with rowsums
//   sum_j(alpha*Ct[r][j]); epilogue ssum init with ewsum.
//   Numerics HW-verified R8/R13: absmax 7.3e-4 < 1.52e-3 threshold.
// Loop shape is exactly R12's (16 unroll-1 bodies, dual streams,
// phase-grouped MFMAs) which ran 8 waves/SIMD spill-free at ~44 live regs.
//
// Kept from R12: rwf in global scratch (L2-resident; LDS 52 KB -> 2 blocks/
// CU -> 8 waves/SIMD), mfma_f32_16x16x16f16 layout-closed chain (C/D
// row=4q+reg == next B-frag k=4q+jj), fragment-ordered conflict-free
// LDS/global reads (base+lane*8), v_cvt_pkrtz packing, tanh scale 2*log2e
// folded into w0/w1/bb and rwf at staging.

typedef _Float16 half4_t __attribute__((ext_vector_type(4)));
typedef __fp16   fp16x2  __attribute__((ext_vector_type(2)));
typedef float    float4_t __attribute__((ext_vector_type(4)));

#define TANH_SCALE 2.885390081777927f  // 2*log2(e); exp2(S*x) == exp(2x)
#define MFMA16 __builtin_amdgcn_mfma_f32_16x16x16f16
#define NFRAG (3 * 16 * 2 * 64)        // 6144 half4 entries per matrix

namespace {

struct alignas(16) Smem {
  // entry index e = ((k*16+t)*2+sel)*64+lane ; one half4 (8 B) per lane.
  half4_t ctf[NFRAG];               // 48 KB: -2 * alpha * Ct[sel*16+m][16t+4q+jj]
  float w0[256], w1[256], bb[256];  // pre-scaled by S
  float ew[256];                    // -2 * end_w
  float rsC[3 * 32];                // rowsums: sum_j alpha*Ct[r][j]
};

__device__ __forceinline__ half4_t pack4(float4_t v) {
  union { fp16x2 f2[2]; half4_t h4; } u;
  u.f2[0] = __builtin_amdgcn_cvt_pkrtz(v.x, v.y);
  u.f2[1] = __builtin_amdgcn_cvt_pkrtz(v.z, v.w);
  return u.h4;
}

// inv = 1/(1+exp2(y)); tanh(x) = 1 - 2*inv (the -2/+1 live in weights/sums).
__device__ __forceinline__ float inv_pre(float y) {
  return __builtin_amdgcn_rcpf(__builtin_amdgcn_exp2f(y) + 1.0f);
}

__device__ __forceinline__ half4_t inv4(float4_t v) {
  float4_t r;
  r.x = inv_pre(v.x); r.y = inv_pre(v.y);
  r.z = inv_pre(v.z); r.w = inv_pre(v.w);
  return pack4(r);
}

// ---- pre-kernel: stage rwf fragments (S-prescaled fp16) into d_ws ----
__global__ __launch_bounds__(1024) void stage_rwf(
    const float* __restrict__ r0, const float* __restrict__ r1,
    const float* __restrict__ r2, half4_t* __restrict__ ws)
{
  const int e = blockIdx.x * 1024 + threadIdx.x;
  if (e >= NFRAG) return;
  const int lane_ = e & 63;
  const int sel   = (e >> 6) & 1;
  const int t_    = (e >> 7) & 15;
  const int k_    = e >> 11;
  const int m_ = lane_ & 15, q_ = lane_ >> 4;
  const float* rk = (k_ == 0) ? r0 : (k_ == 1) ? r1 : r2;
  const int j = 16 * t_ + m_;
  const int rr = sel * 16 + 4 * q_;
  half4_t v;
  v.x = (_Float16)(rk[j * 32 + rr + 0] * TANH_SCALE);
  v.y = (_Float16)(rk[j * 32 + rr + 1] * TANH_SCALE);
  v.z = (_Float16)(rk[j * 32 + rr + 2] * TANH_SCALE);
  v.w = (_Float16)(rk[j * 32 + rr + 3] * TANH_SCALE);
  ws[e] = v;
}

__global__ __launch_bounds__(1024)
__attribute__((amdgpu_waves_per_eu(8, 8)))
void pinn_fused(
    const float* __restrict__ xg, const float* __restrict__ tg,
    const float* __restrict__ sw, const float* __restrict__ sb,
    const float* __restrict__ ewp, const float* __restrict__ ebp,
    const float* __restrict__ c0, const float* __restrict__ c1,
    const float* __restrict__ c2, const float* __restrict__ a0,
    const float* __restrict__ a1, const float* __restrict__ a2,
    const half4_t* __restrict__ rwg, float* __restrict__ out, int n)
{
  __shared__ Smem sm;
  const int tid = threadIdx.x;

  // ---- stage ctf (with -2*alpha folded) into fragment-ordered LDS ----
  for (int e = tid; e < NFRAG; e += 1024) {
    const int lane_ = e & 63;
    const int sel   = (e >> 6) & 1;
    const int t_    = (e >> 7) & 15;
    const int k_    = e >> 11;
    const int m_ = lane_ & 15, q_ = lane_ >> 4;
    const float* ck = (k_ == 0) ? c0 : (k_ == 1) ? c1 : c2;
    const float* ak = (k_ == 0) ? a0 : (k_ == 1) ? a1 : a2;
    const int r = sel * 16 + m_;
    const float av = ak[r] * -2.0f;
    const int j0 = 16 * t_ + 4 * q_;
    half4_t v;
    v.x = (_Float16)(ck[(j0 + 0) * 32 + r] * av);
    v.y = (_Float16)(ck[(j0 + 1) * 32 + r] * av);
    v.z = (_Float16)(ck[(j0 + 2) * 32 + r] * av);
    v.w = (_Float16)(ck[(j0 + 3) * 32 + r] * av);
    sm.ctf[e] = v;
  }
  if (tid < 256) {
    sm.w0[tid] = sw[2 * tid] * TANH_SCALE;
    sm.w1[tid] = sw[2 * tid + 1] * TANH_SCALE;
    sm.bb[tid] = sb[tid] * TANH_SCALE;
    sm.ew[tid] = ewp[tid] * -2.0f;              // fold -2
  }
  __syncthreads();

  // ---- rowsums rsC[k][r] = sum_j alpha*Ct[r][j] = -0.5 * sum(ctf frags) ----
  if (tid < 96) {
    const int k_ = tid >> 5, r = tid & 31;
    const int sel = r >> 4, mm = r & 15;
    float s = 0.0f;
    for (int t = 0; t < 16; ++t)
      for (int qq = 0; qq < 4; ++qq) {
        const half4_t v = sm.ctf[((k_ * 16 + t) * 2 + sel) * 64 + 16 * qq + mm];
        s += (float)v.x + (float)v.y + (float)v.z + (float)v.w;
      }
    sm.rsC[k_ * 32 + r] = -0.5f * s;
  }
  __syncthreads();

  const int wave = tid >> 6;
  const int lane = tid & 63;
  const int m = lane & 15;   // point index (MFMA col / A-row / B-col)
  const int q = lane >> 4;   // quad
  const int wo = 4 * q;      // j = 16t + 4q + jj
  const float ebv = ebp[0];
  const int tiles = n >> 4;

  // per-lane ewsum: out = sum(ew) + sum((-2ew)*inv); sm.ew = -2*ew
  float ewsum = 0.0f;
  for (int t = 0; t < 16; ++t) {
    const float4_t e4 = *(const float4_t*)&sm.ew[t * 16 + wo];
    ewsum += e4.x + e4.y + e4.z + e4.w;
  }
  ewsum *= -0.5f;

  const float4_t z4 = {0.f, 0.f, 0.f, 0.f};  // hoisted MFMA C-operand zero

#pragma unroll 1
  for (int g = (blockIdx.x * 16 + wave) * 2; g < tiles; g += 16384) {
    const int n0 = g * 16;
    const int n1 = n0 + 16;
    const float xm0 = xg[n0 + m], tm0 = tg[n0 + m];
    const float xm1 = xg[n1 + m], tm1 = tg[n1 + m];

    // ---- phase0 fused with GEMM1(k=0); accs init with rowsums(0) ----
    const float4_t rs00 = *(const float4_t*)&sm.rsC[wo];
    const float4_t rs01 = *(const float4_t*)&sm.rsC[16 + wo];
    float4_t a00 = rs00, a01 = rs01, a10 = rs00, a11 = rs01;
    const half4_t* cp0 = &sm.ctf[lane];
#pragma unroll 1
    for (int t = 0; t < 16; ++t) {
      const int cb = t * 16 + wo;
      const float4_t w0v = *(const float4_t*)&sm.w0[cb];
      const float4_t w1v = *(const float4_t*)&sm.w1[cb];
      const float4_t bv  = *(const float4_t*)&sm.bb[cb];
      float4_t z0, z1;
      z0.x = fmaf(xm0, w0v.x, fmaf(tm0, w1v.x, bv.x));
      z1.x = fmaf(xm1, w0v.x, fmaf(tm1, w1v.x, bv.x));
      z0.y = fmaf(xm0, w0v.y, fmaf(tm0, w1v.y, bv.y));
      z1.y = fmaf(xm1, w0v.y, fmaf(tm1, w1v.y, bv.y));
      z0.z = fmaf(xm0, w0v.z, fmaf(tm0, w1v.z, bv.z));
      z1.z = fmaf(xm1, w0v.z, fmaf(tm1, w1v.z, bv.z));
      z0.w = fmaf(xm0, w0v.w, fmaf(tm0, w1v.w, bv.w));
      z1.w = fmaf(xm1, w0v.w, fmaf(tm1, w1v.w, bv.w));
      const half4_t h0 = inv4(z0);
      const half4_t h1 = inv4(z1);
      const half4_t cA = cp0[0], cB = cp0[64];
      a00 = MFMA16(cA, h0, a00, 0, 0, 0);
      a10 = MFMA16(cA, h1, a10, 0, 0, 0);
      a01 = MFMA16(cB, h0, a01, 0, 0, 0);
      a11 = MFMA16(cB, h1, a11, 0, 0, 0);
      cp0 += 128;
    }

#pragma unroll 1
    for (int k = 0; k < 2; ++k) {
      // acc holds true P (rowsum init); pack as next B-frag.
      const half4_t pA0 = pack4(a00), pB0 = pack4(a01);
      const half4_t pA1 = pack4(a10), pB1 = pack4(a11);
      const float4_t rsA = *(const float4_t*)&sm.rsC[(k + 1) * 32 + wo];
      const float4_t rsB = *(const float4_t*)&sm.rsC[(k + 1) * 32 + 16 + wo];
      float4_t n00 = rsA, n01 = rsB, n10 = rsA, n11 = rsB;
      const half4_t* rp = &rwg[k * 2048 + lane];   // global, L2-resident
      const half4_t* cp = &sm.ctf[(k + 1) * 2048 + lane];
#pragma unroll 1
      for (int t = 0; t < 16; ++t) {
        const half4_t rA = rp[0], rB = rp[64];
        const half4_t cA = cp[0], cB = cp[64];
        float4_t u0 = MFMA16(rA, pA0, z4, 0, 0, 0);
        float4_t u1 = MFMA16(rA, pA1, z4, 0, 0, 0);
        u0 = MFMA16(rB, pB0, u0, 0, 0, 0);
        u1 = MFMA16(rB, pB1, u1, 0, 0, 0);
        const half4_t h0 = inv4(u0);
        const half4_t h1 = inv4(u1);
        n00 = MFMA16(cA, h0, n00, 0, 0, 0);
        n10 = MFMA16(cA, h1, n10, 0, 0, 0);
        n01 = MFMA16(cB, h0, n01, 0, 0, 0);
        n11 = MFMA16(cB, h1, n11, 0, 0, 0);
        rp += 128; cp += 128;
      }
      a00 = n00; a01 = n01; a10 = n10; a11 = n11;
    }

    // ---- k=2: GEMM2(2) fused with the end_w dot; ssum init = ewsum ----
    float ssum0 = ewsum, ssum1 = ewsum;
    {
      const half4_t pA0 = pack4(a00), pB0 = pack4(a01);
      const half4_t pA1 = pack4(a10), pB1 = pack4(a11);
      const half4_t* rp = &rwg[2 * 2048 + lane];
#pragma unroll 1
      for (int t = 0; t < 16; ++t) {
        const half4_t rA = rp[0], rB = rp[64];
        const float4_t ev = *(const float4_t*)&sm.ew[t * 16 + wo];  // -2*ew
        float4_t u0 = MFMA16(rA, pA0, z4, 0, 0, 0);
        float4_t u1 = MFMA16(rA, pA1, z4, 0, 0, 0);
        u0 = MFMA16(rB, pB0, u0, 0, 0, 0);
        u1 = MFMA16(rB, pB1, u1, 0, 0, 0);
        ssum0 = fmaf(ev.x, inv_pre(u0.x), ssum0);
        ssum1 = fmaf(ev.x, inv_pre(u1.x), ssum1);
        ssum0 = fmaf(ev.y, inv_pre(u0.y), ssum0);
        ssum1 = fmaf(ev.y, inv_pre(u1.y), ssum1);
        ssum0 = fmaf(ev.z, inv_pre(u0.z), ssum0);
        ssum1 = fmaf(ev.z, inv_pre(u1.z), ssum1);
        ssum0 = fmaf(ev.w, inv_pre(u0.w), ssum0);
        ssum1 = fmaf(ev.w, inv_pre(u1.w), ssum1);
        rp += 128;
      }
    }

    // reduce each stream's partial dot over the 4 quads
    ssum0 += __shfl_xor(ssum0, 16);
    ssum0 += __shfl_xor(ssum0, 32);
    ssum1 += __shfl_xor(ssum1, 16);
    ssum1 += __shfl_xor(ssum1, 32);
    if (lane < 16) {
      out[n0 + m] = ssum0 + ebv;
      out[n1 + m] = ssum1 + ebv;
    }
  }
}

}  // namespace

extern "C" void kernel_launch(void* const* d_in, const int* in_sizes, int n_in,
                              void* d_out, int out_size, void* d_ws, size_t ws_size,
                              hipStream_t stream) {
  const float* xg  = (const float*)d_in[0];
  const float* tg  = (const float*)d_in[1];
  const float* sw  = (const float*)d_in[2];
  const float* sb  = (const float*)d_in[3];
  const float* ewp = (const float*)d_in[4];
  const float* ebp = (const float*)d_in[5];
  const float* c0  = (const float*)d_in[6];
  const float* c1  = (const float*)d_in[7];
  const float* c2  = (const float*)d_in[8];
  const float* r0  = (const float*)d_in[9];
  const float* r1  = (const float*)d_in[10];
  const float* r2  = (const float*)d_in[11];
  const float* a0  = (const float*)d_in[12];
  const float* a1  = (const float*)d_in[13];
  const float* a2  = (const float*)d_in[14];
  float* outp = (float*)d_out;
  half4_t* ws = (half4_t*)d_ws;   // 48 KB of rwf fragments

  const int n = in_sizes[0];  // 262144

  // stage rwf into d_ws (same stream: ordered before the main kernel)
  stage_rwf<<<(NFRAG + 1023) / 1024, 1024, 0, stream>>>(r0, r1, r2, ws);

  pinn_fused<<<512, 1024, 0, stream>>>(xg, tg, sw, sb, ewp, ebp,
                                       c0, c1, c2, a0, a1, a2,
                                       ws, outp, n);
}